// Round 1
// baseline (206.715 us; speedup 1.0000x reference)
//
#include <hip/hip_runtime.h>

// YOLO-v1 loss forward, S=7, B=2, C=20, bs=16384.
// R13 = cross-tile software pipeline. R12's wave_lds_fence was
// fence(seq_cst,"wavefront") -> compiler drains vmcnt(0) every tile ->
// in-flight bytes collapse during LDS+compute (Little's-law bound ~1-3 TB/s,
// NOT a fabric wall; the 6.6 TB/s fills prove transport headroom).
// Changes:
//   * issue NEXT tile's 30 dwordx4 loads right after current tile's regs
//     retire into LDS; loads stay outstanding through extract+compute.
//   * LDS write->read ordering via s_waitcnt lgkmcnt(0) ONLY (vmcnt untouched)
//     + sched_barrier(0) (rule: compiler hoists past inline-asm lgkmcnt).
//   * per-cell extraction (halves live floats; ~210 VGPR peak, spill-free).
//   * NT hint dropped: inputs are L3-resident; latency is what we now hide.
// Accumulation order unchanged -> bitwise-identical result (absmax 0).

#define SS 7
#define CELL_STRIDE 30                         // 5*B + C floats per cell
#define TILE_CELLS 128                         // per wave-private tile
#define TILE_FLOATS (TILE_CELLS * CELL_STRIDE) // 3840 floats = 15360 B
#define NBLOCKS 1280                           // 5 single-wave blocks/CU (30.7 KB LDS)

typedef float vfloat4 __attribute__((ext_vector_type(4)));

// LDS writes complete before cross-lane reads. lgkmcnt only — global
// prefetch loads must stay in flight across this point.
__device__ __forceinline__ void lds_write_read_fence() {
    asm volatile("s_waitcnt lgkmcnt(0)" ::: "memory");
    __builtin_amdgcn_sched_barrier(0);
    __builtin_amdgcn_wave_barrier();
}

// Compiler-order barrier at tile boundary: this tile's ds_reads stay before
// next tile's ds_writes. HW side is safe (same-wave DS ops execute in order).
__device__ __forceinline__ void tile_boundary_fence() {
    asm volatile("" ::: "memory");
    __builtin_amdgcn_wave_barrier();
}

__device__ __forceinline__ void load_tile(const float* __restrict__ preds,
                                          const float* __restrict__ labels,
                                          size_t fbase, int lane,
                                          vfloat4* t, vfloat4* u) {
    const vfloat4* gp = reinterpret_cast<const vfloat4*>(preds  + fbase);
    const vfloat4* gl = reinterpret_cast<const vfloat4*>(labels + fbase);
    #pragma unroll
    for (int k = 0; k < 15; ++k) t[k] = gp[lane + 64 * k];
    #pragma unroll
    for (int k = 0; k < 15; ++k) u[k] = gl[lane + 64 * k];
}

__device__ __forceinline__ float yolo_cell_loss(const float* pv, const float* lv, int cell) {
    const int rem = cell % (SS * SS);
    const float gx = (float)(rem % SS);   // meshgrid 'xy': x = col
    const float gy = (float)(rem / SS);   // y = row

    const float obj = lv[4];
    const float lx = lv[0], ly = lv[1], lw = lv[2], lh = lv[3];
    const float l_cx = (gx + lx) / 7.0f;
    const float l_cy = (gy + ly) / 7.0f;
    const float l_minx = l_cx - lw * 0.5f, l_maxx = l_cx + lw * 0.5f;
    const float l_miny = l_cy - lh * 0.5f, l_maxy = l_cy + lh * 0.5f;
    const float area_l = lw * lh;

    float iou[2], box_err[2], conf[2];
    #pragma unroll
    for (int b = 0; b < 2; ++b) {
        const float px = pv[5 * b + 0], py = pv[5 * b + 1];
        const float pw = pv[5 * b + 2], ph = pv[5 * b + 3];
        conf[b] = pv[5 * b + 4];
        const float p_cx = (gx + px) / 7.0f;
        const float p_cy = (gy + py) / 7.0f;
        const float p_minx = p_cx - pw * 0.5f, p_maxx = p_cx + pw * 0.5f;
        const float p_miny = p_cy - ph * 0.5f, p_maxy = p_cy + ph * 0.5f;
        float iw = fminf(p_maxx, l_maxx) - fmaxf(p_minx, l_minx);
        float ih = fminf(p_maxy, l_maxy) - fmaxf(p_miny, l_miny);
        iw = fmaxf(iw, 0.0f); ih = fmaxf(ih, 0.0f);
        const float inter = iw * ih;
        const float uni = pw * ph + area_l - inter + 1e-10f;
        iou[b] = inter / uni;
        const float dx = px - lx, dy = py - ly;
        const float dw = sqrtf(pw) - sqrtf(lw);
        const float dh = sqrtf(ph) - sqrtf(lh);
        box_err[b] = (dx * dx + dy * dy) + (dw * dw + dh * dh);
    }

    // argmax tie-break: first max wins -> box 1 only if strictly greater
    const int r = (iou[1] > iou[0]) ? 1 : 0;
    const float cr = conf[r], cn = conf[1 - r];

    float loss = obj * (5.0f * box_err[r] + (cr - iou[r]) * (cr - iou[r]));
    loss += 0.5f * ((1.0f - obj) * cr * cr + cn * cn);

    float cls = 0.0f;
    #pragma unroll
    for (int k = 10; k < 30; ++k) {
        const float d = pv[k] - lv[k];
        cls += d * d;
    }
    loss += obj * cls;
    return loss;
}

// extract ONE cell (HALF=0: floats [60*lane,+30); HALF=1: [60*lane+30,+30))
// 8 ds_read_b128 per cell per buffer; boundary v4 (idx 15*lane+7) read by both.
template <int HALF>
__device__ __forceinline__ void extract_cell(const vfloat4* sh4, int lane, float* c) {
    #pragma unroll
    for (int j = 0; j < 8; ++j) {
        const int v4i = HALF * 7 + j;            // 0..7 or 7..14
        const vfloat4 v = sh4[15 * lane + v4i];
        #pragma unroll
        for (int q = 0; q < 4; ++q) {
            const int f = 4 * v4i + q - 30 * HALF;  // compile-time
            if (f >= 0 && f < 30) c[f] = v[q];
        }
    }
}

__global__ __launch_bounds__(64, 1) void yolo_loss_partial(
    const float* __restrict__ preds,
    const float* __restrict__ labels,
    float* __restrict__ partial,
    int ntiles, float inv_bs, int use_atomic)
{
    __shared__ float shP[TILE_FLOATS];       // preds tile  (15360 B)
    __shared__ float shL[TILE_FLOATS];       // labels tile (15360 B)
    vfloat4* shP4 = reinterpret_cast<vfloat4*>(shP);
    vfloat4* shL4 = reinterpret_cast<vfloat4*>(shL);
    const int lane = threadIdx.x;            // 0..63, single-wave block

    float acc = 0.0f;

    int tile = blockIdx.x;
    vfloat4 t[15], u[15];
    if (tile < ntiles)
        load_tile(preds, labels, (size_t)tile * TILE_FLOATS, lane, t, u);

    while (tile < ntiles) {
        const int next = tile + NBLOCKS;

        // ---- phase A: current tile regs -> LDS ----
        // (compiler inserts the data-dependent vmcnt waits here; by steady
        //  state these loads have had a full extract+compute phase in flight)
        #pragma unroll
        for (int k = 0; k < 15; ++k) shP4[lane + 64 * k] = t[k];
        #pragma unroll
        for (int k = 0; k < 15; ++k) shL4[lane + 64 * k] = u[k];
        lds_write_read_fence();              // lgkm only — vmcnt NOT drained

        // ---- phase B: issue NEXT tile's loads; t,u are dead, reuse them ----
        if (next < ntiles)
            load_tile(preds, labels, (size_t)next * TILE_FLOATS, lane, t, u);
        __builtin_amdgcn_sched_barrier(0);   // pin loads before the ds_reads

        // ---- phase C: extract + compute current tile (loads in flight) ----
        const int cellA = tile * TILE_CELLS + 2 * lane;
        {
            float pv[CELL_STRIDE], lv[CELL_STRIDE];
            extract_cell<0>(shP4, lane, pv);
            extract_cell<0>(shL4, lane, lv);
            acc += yolo_cell_loss(pv, lv, cellA);
        }
        {
            float pv[CELL_STRIDE], lv[CELL_STRIDE];
            extract_cell<1>(shP4, lane, pv);
            extract_cell<1>(shL4, lane, lv);
            acc += yolo_cell_loss(pv, lv, cellA + 1);
        }

        tile_boundary_fence();               // reads ordered before next writes
        tile = next;
    }

    acc *= inv_bs;

    // single-wave shuffle reduction
    #pragma unroll
    for (int off = 32; off > 0; off >>= 1)
        acc += __shfl_down(acc, off, 64);

    if (lane == 0) {
        if (use_atomic) atomicAdd(partial, acc);     // fallback: partial==out
        else            partial[blockIdx.x] = acc;
    }
}

__global__ __launch_bounds__(256) void yolo_reduce(
    const float* __restrict__ partial, float* __restrict__ out, int n)
{
    float acc = 0.0f;
    for (int i = threadIdx.x; i < n; i += 256) acc += partial[i];
    #pragma unroll
    for (int off = 32; off > 0; off >>= 1)
        acc += __shfl_down(acc, off, 64);
    __shared__ float wsum[4];
    const int lane = threadIdx.x & 63;
    const int wid  = threadIdx.x >> 6;
    if (lane == 0) wsum[wid] = acc;
    __syncthreads();
    if (threadIdx.x == 0) out[0] = wsum[0] + wsum[1] + wsum[2] + wsum[3];
}

__global__ void yolo_zero_out(float* out) {
    if (threadIdx.x == 0) out[0] = 0.0f;
}

extern "C" void kernel_launch(void* const* d_in, const int* in_sizes, int n_in,
                              void* d_out, int out_size, void* d_ws, size_t ws_size,
                              hipStream_t stream) {
    const float* preds  = (const float*)d_in[0];
    const float* labels = (const float*)d_in[1];
    float* out = (float*)d_out;

    const int ncells = in_sizes[0] / CELL_STRIDE;        // 802816 (divisible by 128)
    const int ntiles = ncells / TILE_CELLS;              // 6272
    const int bs     = ncells / (SS * SS);               // 16384
    const float inv_bs = 1.0f / (float)bs;

    if (ws_size >= NBLOCKS * sizeof(float)) {
        float* partial = (float*)d_ws;
        yolo_loss_partial<<<NBLOCKS, 64, 0, stream>>>(preds, labels, partial,
                                                      ntiles, inv_bs, 0);
        yolo_reduce<<<1, 256, 0, stream>>>(partial, out, NBLOCKS);
    } else {
        yolo_zero_out<<<1, 64, 0, stream>>>(out);
        yolo_loss_partial<<<NBLOCKS, 64, 0, stream>>>(preds, labels, out,
                                                      ntiles, inv_bs, 1);
    }
}

// Round 3
// 190.476 us; speedup vs baseline: 1.0853x; 1.0853x over previous
//
#include <hip/hip_runtime.h>

// YOLO-v1 loss forward, S=7, B=2, C=20, bs=16384.
// R15 = R14 resubmitted (previous round died on container acquisition, not
// the kernel). Cross-tile pipeline + NT loads — one-variable probe vs R13.
// Evidence so far:
//   R12 (NT, burst-drain):   ~58-59 us  = 3.27 TB/s read
//   R13 (no-NT, pipelined):   75 us     = 2.57 TB/s read, FETCH=96MB (half L3)
//   fills: 6.6 TB/s write-only; m13 copy: ~3.15 TB/s read side.
// R13 disproves the concurrency theory (38 MB in flight, still slower) ->
// the wall is the load-return path at ~3.3 TB/s, source-independent; non-NT
// allocation traffic (reads written INTO L2/L3) drags below it. NT restores
// the no-allocate streaming path. Pipeline kept (free; removes burst gaps).
// Accumulation order unchanged -> bitwise-identical result (absmax 0).

#define SS 7
#define CELL_STRIDE 30                         // 5*B + C floats per cell
#define TILE_CELLS 128                         // per wave-private tile
#define TILE_FLOATS (TILE_CELLS * CELL_STRIDE) // 3840 floats = 15360 B
#define NBLOCKS 1280                           // 5 single-wave blocks/CU (30.7 KB LDS)

typedef float vfloat4 __attribute__((ext_vector_type(4)));

// LDS writes complete before cross-lane reads. lgkmcnt only — global
// prefetch loads must stay in flight across this point.
__device__ __forceinline__ void lds_write_read_fence() {
    asm volatile("s_waitcnt lgkmcnt(0)" ::: "memory");
    __builtin_amdgcn_sched_barrier(0);
    __builtin_amdgcn_wave_barrier();
}

// Compiler-order barrier at tile boundary: this tile's ds_reads stay before
// next tile's ds_writes. HW side is safe (same-wave DS ops execute in order).
__device__ __forceinline__ void tile_boundary_fence() {
    asm volatile("" ::: "memory");
    __builtin_amdgcn_wave_barrier();
}

__device__ __forceinline__ vfloat4 nt_load_f4(const vfloat4* p) {
    return __builtin_nontemporal_load(p);
}

__device__ __forceinline__ void load_tile(const float* __restrict__ preds,
                                          const float* __restrict__ labels,
                                          size_t fbase, int lane,
                                          vfloat4* t, vfloat4* u) {
    const vfloat4* gp = reinterpret_cast<const vfloat4*>(preds  + fbase);
    const vfloat4* gl = reinterpret_cast<const vfloat4*>(labels + fbase);
    #pragma unroll
    for (int k = 0; k < 15; ++k) t[k] = nt_load_f4(gp + lane + 64 * k);
    #pragma unroll
    for (int k = 0; k < 15; ++k) u[k] = nt_load_f4(gl + lane + 64 * k);
}

__device__ __forceinline__ float yolo_cell_loss(const float* pv, const float* lv, int cell) {
    const int rem = cell % (SS * SS);
    const float gx = (float)(rem % SS);   // meshgrid 'xy': x = col
    const float gy = (float)(rem / SS);   // y = row

    const float obj = lv[4];
    const float lx = lv[0], ly = lv[1], lw = lv[2], lh = lv[3];
    const float l_cx = (gx + lx) / 7.0f;
    const float l_cy = (gy + ly) / 7.0f;
    const float l_minx = l_cx - lw * 0.5f, l_maxx = l_cx + lw * 0.5f;
    const float l_miny = l_cy - lh * 0.5f, l_maxy = l_cy + lh * 0.5f;
    const float area_l = lw * lh;

    float iou[2], box_err[2], conf[2];
    #pragma unroll
    for (int b = 0; b < 2; ++b) {
        const float px = pv[5 * b + 0], py = pv[5 * b + 1];
        const float pw = pv[5 * b + 2], ph = pv[5 * b + 3];
        conf[b] = pv[5 * b + 4];
        const float p_cx = (gx + px) / 7.0f;
        const float p_cy = (gy + py) / 7.0f;
        const float p_minx = p_cx - pw * 0.5f, p_maxx = p_cx + pw * 0.5f;
        const float p_miny = p_cy - ph * 0.5f, p_maxy = p_cy + ph * 0.5f;
        float iw = fminf(p_maxx, l_maxx) - fmaxf(p_minx, l_minx);
        float ih = fminf(p_maxy, l_maxy) - fmaxf(p_miny, l_miny);
        iw = fmaxf(iw, 0.0f); ih = fmaxf(ih, 0.0f);
        const float inter = iw * ih;
        const float uni = pw * ph + area_l - inter + 1e-10f;
        iou[b] = inter / uni;
        const float dx = px - lx, dy = py - ly;
        const float dw = sqrtf(pw) - sqrtf(lw);
        const float dh = sqrtf(ph) - sqrtf(lh);
        box_err[b] = (dx * dx + dy * dy) + (dw * dw + dh * dh);
    }

    // argmax tie-break: first max wins -> box 1 only if strictly greater
    const int r = (iou[1] > iou[0]) ? 1 : 0;
    const float cr = conf[r], cn = conf[1 - r];

    float loss = obj * (5.0f * box_err[r] + (cr - iou[r]) * (cr - iou[r]));
    loss += 0.5f * ((1.0f - obj) * cr * cr + cn * cn);

    float cls = 0.0f;
    #pragma unroll
    for (int k = 10; k < 30; ++k) {
        const float d = pv[k] - lv[k];
        cls += d * d;
    }
    loss += obj * cls;
    return loss;
}

// extract ONE cell (HALF=0: floats [60*lane,+30); HALF=1: [60*lane+30,+30))
// 8 ds_read_b128 per cell per buffer; boundary v4 (idx 15*lane+7) read by both.
template <int HALF>
__device__ __forceinline__ void extract_cell(const vfloat4* sh4, int lane, float* c) {
    #pragma unroll
    for (int j = 0; j < 8; ++j) {
        const int v4i = HALF * 7 + j;            // 0..7 or 7..14
        const vfloat4 v = sh4[15 * lane + v4i];
        #pragma unroll
        for (int q = 0; q < 4; ++q) {
            const int f = 4 * v4i + q - 30 * HALF;  // compile-time
            if (f >= 0 && f < 30) c[f] = v[q];
        }
    }
}

__global__ __launch_bounds__(64, 1) void yolo_loss_partial(
    const float* __restrict__ preds,
    const float* __restrict__ labels,
    float* __restrict__ partial,
    int ntiles, float inv_bs, int use_atomic)
{
    __shared__ float shP[TILE_FLOATS];       // preds tile  (15360 B)
    __shared__ float shL[TILE_FLOATS];       // labels tile (15360 B)
    vfloat4* shP4 = reinterpret_cast<vfloat4*>(shP);
    vfloat4* shL4 = reinterpret_cast<vfloat4*>(shL);
    const int lane = threadIdx.x;            // 0..63, single-wave block

    float acc = 0.0f;

    int tile = blockIdx.x;
    vfloat4 t[15], u[15];
    if (tile < ntiles)
        load_tile(preds, labels, (size_t)tile * TILE_FLOATS, lane, t, u);

    while (tile < ntiles) {
        const int next = tile + NBLOCKS;

        // ---- phase A: current tile regs -> LDS ----
        // (compiler inserts the data-dependent vmcnt waits here; by steady
        //  state these loads have had a full extract+compute phase in flight)
        #pragma unroll
        for (int k = 0; k < 15; ++k) shP4[lane + 64 * k] = t[k];
        #pragma unroll
        for (int k = 0; k < 15; ++k) shL4[lane + 64 * k] = u[k];
        lds_write_read_fence();              // lgkm only — vmcnt NOT drained

        // ---- phase B: issue NEXT tile's loads; t,u are dead, reuse them ----
        if (next < ntiles)
            load_tile(preds, labels, (size_t)next * TILE_FLOATS, lane, t, u);
        __builtin_amdgcn_sched_barrier(0);   // pin loads before the ds_reads

        // ---- phase C: extract + compute current tile (loads in flight) ----
        const int cellA = tile * TILE_CELLS + 2 * lane;
        {
            float pv[CELL_STRIDE], lv[CELL_STRIDE];
            extract_cell<0>(shP4, lane, pv);
            extract_cell<0>(shL4, lane, lv);
            acc += yolo_cell_loss(pv, lv, cellA);
        }
        {
            float pv[CELL_STRIDE], lv[CELL_STRIDE];
            extract_cell<1>(shP4, lane, pv);
            extract_cell<1>(shL4, lane, lv);
            acc += yolo_cell_loss(pv, lv, cellA + 1);
        }

        tile_boundary_fence();               // reads ordered before next writes
        tile = next;
    }

    acc *= inv_bs;

    // single-wave shuffle reduction
    #pragma unroll
    for (int off = 32; off > 0; off >>= 1)
        acc += __shfl_down(acc, off, 64);

    if (lane == 0) {
        if (use_atomic) atomicAdd(partial, acc);     // fallback: partial==out
        else            partial[blockIdx.x] = acc;
    }
}

__global__ __launch_bounds__(256) void yolo_reduce(
    const float* __restrict__ partial, float* __restrict__ out, int n)
{
    float acc = 0.0f;
    for (int i = threadIdx.x; i < n; i += 256) acc += partial[i];
    #pragma unroll
    for (int off = 32; off > 0; off >>= 1)
        acc += __shfl_down(acc, off, 64);
    __shared__ float wsum[4];
    const int lane = threadIdx.x & 63;
    const int wid  = threadIdx.x >> 6;
    if (lane == 0) wsum[wid] = acc;
    __syncthreads();
    if (threadIdx.x == 0) out[0] = wsum[0] + wsum[1] + wsum[2] + wsum[3];
}

__global__ void yolo_zero_out(float* out) {
    if (threadIdx.x == 0) out[0] = 0.0f;
}

extern "C" void kernel_launch(void* const* d_in, const int* in_sizes, int n_in,
                              void* d_out, int out_size, void* d_ws, size_t ws_size,
                              hipStream_t stream) {
    const float* preds  = (const float*)d_in[0];
    const float* labels = (const float*)d_in[1];
    float* out = (float*)d_out;

    const int ncells = in_sizes[0] / CELL_STRIDE;        // 802816 (divisible by 128)
    const int ntiles = ncells / TILE_CELLS;              // 6272
    const int bs     = ncells / (SS * SS);               // 16384
    const float inv_bs = 1.0f / (float)bs;

    if (ws_size >= NBLOCKS * sizeof(float)) {
        float* partial = (float*)d_ws;
        yolo_loss_partial<<<NBLOCKS, 64, 0, stream>>>(preds, labels, partial,
                                                      ntiles, inv_bs, 0);
        yolo_reduce<<<1, 256, 0, stream>>>(partial, out, NBLOCKS);
    } else {
        yolo_zero_out<<<1, 64, 0, stream>>>(out);
        yolo_loss_partial<<<NBLOCKS, 64, 0, stream>>>(preds, labels, out,
                                                      ntiles, inv_bs, 1);
    }
}